// Round 11
// baseline (322.526 us; speedup 1.0000x reference)
//
#include <hip/hip_runtime.h>
#include <hip/hip_bf16.h>
#include <hip/hip_fp16.h>
#include <math.h>

#define NN 20000
#define NE 320000
#define SLOT 64  // padded-CSR slots per node; P(deg>64) ~ 1e-18 at mean 16

typedef __attribute__((ext_vector_type(8))) short bf16x8;
typedef __attribute__((ext_vector_type(4))) float f32x4;

__device__ inline float bf2f_lo(uint v) {
    union { uint i; float f; } c; c.i = v << 16; return c.f;
}
__device__ inline float bf2f_hi(uint v) {
    union { uint i; float f; } c; c.i = v & 0xffff0000u; return c.f;
}
__device__ inline ushort f2bf(float f) {
    __hip_bfloat16 h = __float2bfloat16(f);
    return *reinterpret_cast<ushort*>(&h);
}
__device__ inline uint pack2bf(float a, float b) {
    return (uint)f2bf(a) | ((uint)f2bf(b) << 16);
}
__device__ inline float2 h2f2(uint u) {  // 2 packed halves -> 2 floats
    union { uint i; __half2 h; } c; c.i = u;
    return __half22float2(c.h);
}
__device__ inline ushort f2h(float f) {
    __half h = __float2half_rn(f);
    return *reinterpret_cast<ushort*>(&h);
}

__device__ inline float fast_tanh(float x) {
    x = fminf(fmaxf(x, -9.f), 9.f);
    float e = __expf(2.f * x);
    return 1.f - 2.f / (e + 1.f);
}

struct EdgeParams {
    const float *pw0, *pb0, *mu0, *is0;
    const float *pw1, *pb1, *mu1, *is1;
    const float *pw2, *pb2, *mu2, *is2;
};

__device__ inline void layer_w(float p0, float p1, const float* pw, const float* pb,
                               const float* mu, const float* is, float* out4) {
    float u0 = fast_tanh(p0 * pw[0] + p1 * pw[2] + pb[0]);
    float u1 = fast_tanh(p0 * pw[1] + p1 * pw[3] + pb[1]);
#pragma unroll
    for (int k = 0; k < 4; ++k) {
        float d0 = (u0 - mu[k * 2 + 0]) * is[k * 2 + 0];
        float d1 = (u1 - mu[k * 2 + 1]) * is[k * 2 + 1];
        out4[k] = __expf(-0.5f * (d0 * d0 + d1 * d1));
    }
}

// ---- prep: edge records (blocks 0..1249) + weight transpose (1250..1889)
//      + features->bf16 (1890..2514) ----
__global__ void fill_prep(const int* __restrict__ dst, const int* __restrict__ src,
                          const float* __restrict__ pseudo, EdgeParams P,
                          int* __restrict__ cursor, uint* __restrict__ recs,
                          const float* __restrict__ features, ushort* __restrict__ fbf,
                          const float* __restrict__ f0, const float* __restrict__ f1,
                          const float* __restrict__ f2, ushort* __restrict__ w0,
                          ushort* __restrict__ w1, ushort* __restrict__ w2) {
    int bid = blockIdx.x;
    if (bid < 1250) {
        int e = bid * 256 + threadIdx.x;  // 1250*256 == NE exactly
        int n = dst[e];
        int pos = atomicAdd(&cursor[n], 1);
        if (pos < SLOT) {
            size_t slot = (size_t)n * SLOT + pos;
            float2 p = *(const float2*)(pseudo + (size_t)e * 2);  // contiguous read
            float w[4];
            uint pk0x, pk0y, pk1x, pk1y, pk2x, pk2y;
            layer_w(p.x, p.y, P.pw0, P.pb0, P.mu0, P.is0, w);
            pk0x = (uint)f2h(w[0]) | ((uint)f2h(w[1]) << 16);
            pk0y = (uint)f2h(w[2]) | ((uint)f2h(w[3]) << 16);
            layer_w(p.x, p.y, P.pw1, P.pb1, P.mu1, P.is1, w);
            pk1x = (uint)f2h(w[0]) | ((uint)f2h(w[1]) << 16);
            pk1y = (uint)f2h(w[2]) | ((uint)f2h(w[3]) << 16);
            layer_w(p.x, p.y, P.pw2, P.pb2, P.mu2, P.is2, w);
            pk2x = (uint)f2h(w[0]) | ((uint)f2h(w[1]) << 16);
            pk2y = (uint)f2h(w[2]) | ((uint)f2h(w[3]) << 16);
            uint* r = recs + slot * 8;
            *(uint4*)(r + 0) = make_uint4((uint)src[e], 0u, pk0x, pk0y);
            *(uint4*)(r + 4) = make_uint4(pk1x, pk1y, pk2x, pk2y);
        }
    } else if (bid < 1890) {
        int idx = (bid - 1250) * 256 + threadIdx.x;  // 640 blocks cover 163840 exactly
        const float* srcp;
        ushort* dstp;
        int din, KD, li;
        if (idx < 128 * 256) {
            srcp = f0; dstp = w0; din = 64; KD = 256; li = idx;
        } else if (idx < 128 * 256 + 128 * 512) {
            srcp = f1; dstp = w1; din = 128; KD = 512; li = idx - 128 * 256;
        } else {
            srcp = f2; dstp = w2; din = 128; KD = 512; li = idx - 128 * 256 - 128 * 512;
        }
        int n = li / KD;
        int r = li - n * KD;
        int k = r / din;
        int d = r - k * din;
        dstp[li] = f2bf(srcp[d * 512 + k * 128 + n]);
    } else {
        // features f32 -> bf16: 20000*64 = 1.28M elems, 8 per thread, 625 blocks exact
        int idx = (bid - 1890) * 256 + threadIdx.x;  // < 160000
        size_t b8 = (size_t)idx * 8;
        float4 a = *(const float4*)(features + b8);
        float4 b = *(const float4*)(features + b8 + 4);
        uint4 o;
        o.x = pack2bf(a.x, a.y);
        o.y = pack2bf(a.z, a.w);
        o.z = pack2bf(b.x, b.y);
        o.w = pack2bf(b.z, b.w);
        *(uint4*)(fbf + b8) = o;
    }
}

// ---------------- fused layer (R8 pair-gather) + phase-ablation probes ----------------
// PROBE=0: normal. PROBE=1: agg-phase x2, GEMM skipped. PROBE=2: GEMM-phase x2, agg skipped.
template <int DIN, bool OUTBF, int PROBE>
__global__ __launch_bounds__(1024, 4) void layer_fused(
    const ushort* __restrict__ hbf, const int* __restrict__ cursor,
    const uint* __restrict__ recs, int woff,
    const ushort* __restrict__ Bt, const float* __restrict__ bias,
    void* __restrict__ hout) {
    constexpr int KD = 4 * DIN;
    constexpr int PITCH = KD + 8;   // ushorts; 16B-aligned rows
    constexpr int B = 8;            // pairs per batch -> 16 edges
    constexpr int FPL = DIN / 32;   // features per lane (2 or 4)
    __shared__ __align__(16) ushort Ts[16 * PITCH];
    int wv = threadIdx.x >> 6, lane = threadIdx.x & 63;
    int l16 = lane & 15, quad = lane >> 4;
    int half = lane >> 5, l32 = lane & 31;
    int nb = blockIdx.x * 16;
    int n = nb + wv;

    if (PROBE != 2) {
        int deg = __builtin_amdgcn_readfirstlane(cursor[n]);
        deg = deg < SLOT ? deg : SLOT;  // safety clamp
        size_t base = (size_t)n * SLOT;

        float acc[4 * FPL];
#pragma unroll
        for (int j = 0; j < 4 * FPL; ++j) acc[j] = 0.f;

        for (int rep = 0; rep < (PROBE == 1 ? 2 : 1); ++rep) {
            for (int i = 0; i < deg; i += 2 * B) {
                int s[B];
                uint wlo[B], whi[B];
                uint2 hv[B];  // DIN==64 uses only .x
#pragma unroll
                for (int u = 0; u < B; ++u) {
                    int ii = i + 2 * u + half;  // uniform within each half-wave
                    bool ok = ii < deg;
                    size_t idx = base + (ok ? ii : 0);
                    const uint* r = recs + idx * 8;
                    s[u] = (int)r[0];
                    uint2 wp = *(const uint2*)(r + woff);
                    wlo[u] = ok ? wp.x : 0u;
                    whi[u] = ok ? wp.y : 0u;
                }
#pragma unroll
                for (int u = 0; u < B; ++u) {
                    const ushort* row = hbf + (size_t)s[u] * DIN + l32 * FPL;
                    if (DIN == 64)
                        hv[u].x = *(const uint*)row;
                    else
                        hv[u] = *(const uint2*)row;
                }
#pragma unroll
                for (int u = 0; u < B; ++u) {
                    float2 wa = h2f2(wlo[u]);
                    float2 wb = h2f2(whi[u]);
                    float w0 = wa.x, w1 = wa.y, w2 = wb.x, w3 = wb.y;
                    float fx0 = bf2f_lo(hv[u].x), fx1 = bf2f_hi(hv[u].x);
                    if (DIN == 64) {
                        acc[0] += w0 * fx0; acc[1] += w0 * fx1;
                        acc[2] += w1 * fx0; acc[3] += w1 * fx1;
                        acc[4] += w2 * fx0; acc[5] += w2 * fx1;
                        acc[6] += w3 * fx0; acc[7] += w3 * fx1;
                    } else {
                        float fx2 = bf2f_lo(hv[u].y), fx3 = bf2f_hi(hv[u].y);
                        acc[0] += w0 * fx0;  acc[1] += w0 * fx1;
                        acc[2] += w0 * fx2;  acc[3] += w0 * fx3;
                        acc[4] += w1 * fx0;  acc[5] += w1 * fx1;
                        acc[6] += w1 * fx2;  acc[7] += w1 * fx3;
                        acc[8] += w2 * fx0;  acc[9] += w2 * fx1;
                        acc[10] += w2 * fx2; acc[11] += w2 * fx3;
                        acc[12] += w3 * fx0; acc[13] += w3 * fx1;
                        acc[14] += w3 * fx2; acc[15] += w3 * fx3;
                    }
                }
            }
            if (PROBE == 1) asm volatile("" ::: "memory");
        }
        // cross-half combine
#pragma unroll
        for (int j = 0; j < 4 * FPL; ++j) acc[j] += __shfl_xor(acc[j], 32);

        if (half == 0) {
#pragma unroll
            for (int k = 0; k < 4; ++k) {
                if (DIN == 64) {
                    ushort2 p;
                    p.x = f2bf(acc[k * 2 + 0]);
                    p.y = f2bf(acc[k * 2 + 1]);
                    *(ushort2*)(Ts + wv * PITCH + k * DIN + l32 * 2) = p;
                } else {
                    ushort4 p;
                    p.x = f2bf(acc[k * 4 + 0]);
                    p.y = f2bf(acc[k * 4 + 1]);
                    p.z = f2bf(acc[k * 4 + 2]);
                    p.w = f2bf(acc[k * 4 + 3]);
                    *(ushort4*)(Ts + wv * PITCH + k * DIN + l32 * 4) = p;
                }
            }
        }
    } else {
        // PROBE==2: replace agg with Ts zero-fill
        for (int t = threadIdx.x; t < 16 * PITCH; t += 1024) Ts[t] = 0;
    }
    __syncthreads();

    if (PROBE == 1) {
        // consume Ts so agg writes stay live; skip GEMM
        if (threadIdx.x < 256)
            ((ushort*)hout)[(size_t)blockIdx.x * 256 + threadIdx.x] = Ts[threadIdx.x];
        return;
    }

    // ---- GEMM phase: waves 0..7, each 16 rows x 16 cols ----
    if (wv < 8) {
        int c0 = wv * 16;
        f32x4 acc2 = (f32x4){0.f, 0.f, 0.f, 0.f};
        for (int rep = 0; rep < (PROBE == 2 ? 2 : 1); ++rep) {
#pragma unroll 4
            for (int k0 = 0; k0 < KD; k0 += 32) {
                bf16x8 af = *(const bf16x8*)(Ts + l16 * PITCH + k0 + quad * 8);
                bf16x8 bfr = *(const bf16x8*)(Bt + (size_t)(c0 + l16) * KD + k0 + quad * 8);
                acc2 = __builtin_amdgcn_mfma_f32_16x16x32_bf16(af, bfr, acc2, 0, 0, 0);
            }
            if (PROBE == 2) asm volatile("" ::: "memory");
        }
        int gn = c0 + l16;
        float bv = bias[gn];
#pragma unroll
        for (int i = 0; i < 4; ++i) {
            int gm = nb + quad * 4 + i;
            float val = acc2[i] + bv;
            if (OUTBF)
                ((ushort*)hout)[(size_t)gm * 128 + gn] = f2bf(val);
            else
                ((float*)hout)[(size_t)gm * 128 + gn] = val;
        }
    }
}

extern "C" void kernel_launch(void* const* d_in, const int* in_sizes, int n_in,
                              void* d_out, int out_size, void* d_ws, size_t ws_size,
                              hipStream_t stream) {
    const float* features = (const float*)d_in[0];
    const float* pseudo = (const float*)d_in[1];
    const int* src = (const int*)d_in[2];
    const int* dst = (const int*)d_in[3];
    const float* fc_w[3] = {(const float*)d_in[4], (const float*)d_in[10], (const float*)d_in[16]};
    const float* mu[3] = {(const float*)d_in[5], (const float*)d_in[11], (const float*)d_in[17]};
    const float* isg[3] = {(const float*)d_in[6], (const float*)d_in[12], (const float*)d_in[18]};
    const float* bias[3] = {(const float*)d_in[7], (const float*)d_in[13], (const float*)d_in[19]};
    const float* pw[3] = {(const float*)d_in[8], (const float*)d_in[14], (const float*)d_in[20]};
    const float* pb[3] = {(const float*)d_in[9], (const float*)d_in[15], (const float*)d_in[21]};

    char* ws = (char*)d_ws;
    auto alloc = [&](size_t bytes) -> void* {
        void* p = (void*)ws;
        ws += (bytes + 255) & ~(size_t)255;
        return p;
    };
    int* cursor = (int*)alloc((size_t)NN * 4);
    uint* recs = (uint*)alloc((size_t)NN * SLOT * 32);   // 32B record per slot
    ushort* fbf = (ushort*)alloc((size_t)NN * 64 * 2);   // features in bf16
    ushort* w2t_0 = (ushort*)alloc((size_t)128 * 256 * 2);
    ushort* w2t_1 = (ushort*)alloc((size_t)128 * 512 * 2);
    ushort* w2t_2 = (ushort*)alloc((size_t)128 * 512 * 2);
    ushort* h1 = (ushort*)alloc((size_t)NN * 128 * 2);
    ushort* h2 = (ushort*)alloc((size_t)NN * 128 * 2);
    ushort* dummy = (ushort*)alloc((size_t)NN * 128 * 2);  // probe sink

    hipMemsetAsync(cursor, 0, (size_t)NN * 4, stream);
    EdgeParams P;
    P.pw0 = pw[0]; P.pb0 = pb[0]; P.mu0 = mu[0]; P.is0 = isg[0];
    P.pw1 = pw[1]; P.pb1 = pb[1]; P.mu1 = mu[1]; P.is1 = isg[1];
    P.pw2 = pw[2]; P.pb2 = pb[2]; P.mu2 = mu[2]; P.is2 = isg[2];
    fill_prep<<<2515, 256, 0, stream>>>(dst, src, pseudo, P, cursor, recs, features, fbf,
                                        fc_w[0], fc_w[1], fc_w[2], w2t_0, w2t_1, w2t_2);

    const int GB = NN / 16;  // 1250 blocks, 16 waves each, 1 node/wave

    layer_fused<64, true, 0><<<GB, 1024, 0, stream>>>(
        fbf, cursor, recs, 2, w2t_0, bias[0], h1);
    layer_fused<128, true, 0><<<GB, 1024, 0, stream>>>(
        h1, cursor, recs, 4, w2t_1, bias[1], h2);
    layer_fused<128, false, 0><<<GB, 1024, 0, stream>>>(
        h2, cursor, recs, 6, w2t_2, bias[2], (float*)d_out);

    // ---- ablation probes (this round only): layer-2 config -> dummy ----
    layer_fused<128, true, 1><<<GB, 1024, 0, stream>>>(   // agg x2, no GEMM
        h1, cursor, recs, 4, w2t_1, bias[1], dummy);
    layer_fused<128, true, 2><<<GB, 1024, 0, stream>>>(   // GEMM x2, no agg
        h1, cursor, recs, 4, w2t_1, bias[1], dummy);
}

// Round 12
// 259.851 us; speedup vs baseline: 1.2412x; 1.2412x over previous
//
#include <hip/hip_runtime.h>
#include <hip/hip_bf16.h>
#include <hip/hip_fp16.h>
#include <math.h>

#define NN 20000
#define NE 320000
#define SLOT 64  // padded-CSR slots per node; P(deg>64) ~ 1e-18 at mean 16

typedef __attribute__((ext_vector_type(8))) short bf16x8;
typedef __attribute__((ext_vector_type(4))) float f32x4;

__device__ inline float bf2f_lo(uint v) {
    union { uint i; float f; } c; c.i = v << 16; return c.f;
}
__device__ inline float bf2f_hi(uint v) {
    union { uint i; float f; } c; c.i = v & 0xffff0000u; return c.f;
}
__device__ inline ushort f2bf(float f) {
    __hip_bfloat16 h = __float2bfloat16(f);
    return *reinterpret_cast<ushort*>(&h);
}
__device__ inline uint pack2bf(float a, float b) {
    return (uint)f2bf(a) | ((uint)f2bf(b) << 16);
}
__device__ inline float2 h2f2(uint u) {  // 2 packed halves -> 2 floats
    union { uint i; __half2 h; } c; c.i = u;
    return __half22float2(c.h);
}
__device__ inline ushort f2h(float f) {
    __half h = __float2half_rn(f);
    return *reinterpret_cast<ushort*>(&h);
}

__device__ inline float fast_tanh(float x) {
    x = fminf(fmaxf(x, -9.f), 9.f);
    float e = __expf(2.f * x);
    return 1.f - 2.f / (e + 1.f);
}

struct EdgeParams {
    const float *pw0, *pb0, *mu0, *is0;
    const float *pw1, *pb1, *mu1, *is1;
    const float *pw2, *pb2, *mu2, *is2;
};

__device__ inline void layer_w(float p0, float p1, const float* pw, const float* pb,
                               const float* mu, const float* is, float* out4) {
    float u0 = fast_tanh(p0 * pw[0] + p1 * pw[2] + pb[0]);
    float u1 = fast_tanh(p0 * pw[1] + p1 * pw[3] + pb[1]);
#pragma unroll
    for (int k = 0; k < 4; ++k) {
        float d0 = (u0 - mu[k * 2 + 0]) * is[k * 2 + 0];
        float d1 = (u1 - mu[k * 2 + 1]) * is[k * 2 + 1];
        out4[k] = __expf(-0.5f * (d0 * d0 + d1 * d1));
    }
}

// ---- prep: edge records (blocks 0..1249) + weight transpose (1250..1889)
//      + features->bf16 (1890..2514) ----
__global__ void fill_prep(const int* __restrict__ dst, const int* __restrict__ src,
                          const float* __restrict__ pseudo, EdgeParams P,
                          int* __restrict__ cursor, uint* __restrict__ recs,
                          const float* __restrict__ features, ushort* __restrict__ fbf,
                          const float* __restrict__ f0, const float* __restrict__ f1,
                          const float* __restrict__ f2, ushort* __restrict__ w0,
                          ushort* __restrict__ w1, ushort* __restrict__ w2) {
    int bid = blockIdx.x;
    if (bid < 1250) {
        int e = bid * 256 + threadIdx.x;  // 1250*256 == NE exactly
        int n = dst[e];
        int pos = atomicAdd(&cursor[n], 1);
        if (pos < SLOT) {
            size_t slot = (size_t)n * SLOT + pos;
            float2 p = *(const float2*)(pseudo + (size_t)e * 2);  // contiguous read
            float w[4];
            uint pk0x, pk0y, pk1x, pk1y, pk2x, pk2y;
            layer_w(p.x, p.y, P.pw0, P.pb0, P.mu0, P.is0, w);
            pk0x = (uint)f2h(w[0]) | ((uint)f2h(w[1]) << 16);
            pk0y = (uint)f2h(w[2]) | ((uint)f2h(w[3]) << 16);
            layer_w(p.x, p.y, P.pw1, P.pb1, P.mu1, P.is1, w);
            pk1x = (uint)f2h(w[0]) | ((uint)f2h(w[1]) << 16);
            pk1y = (uint)f2h(w[2]) | ((uint)f2h(w[3]) << 16);
            layer_w(p.x, p.y, P.pw2, P.pb2, P.mu2, P.is2, w);
            pk2x = (uint)f2h(w[0]) | ((uint)f2h(w[1]) << 16);
            pk2y = (uint)f2h(w[2]) | ((uint)f2h(w[3]) << 16);
            uint* r = recs + slot * 8;
            *(uint4*)(r + 0) = make_uint4((uint)src[e], 0u, pk0x, pk0y);
            *(uint4*)(r + 4) = make_uint4(pk1x, pk1y, pk2x, pk2y);
        }
    } else if (bid < 1890) {
        int idx = (bid - 1250) * 256 + threadIdx.x;  // 640 blocks cover 163840 exactly
        const float* srcp;
        ushort* dstp;
        int din, KD, li;
        if (idx < 128 * 256) {
            srcp = f0; dstp = w0; din = 64; KD = 256; li = idx;
        } else if (idx < 128 * 256 + 128 * 512) {
            srcp = f1; dstp = w1; din = 128; KD = 512; li = idx - 128 * 256;
        } else {
            srcp = f2; dstp = w2; din = 128; KD = 512; li = idx - 128 * 256 - 128 * 512;
        }
        int n = li / KD;
        int r = li - n * KD;
        int k = r / din;
        int d = r - k * din;
        dstp[li] = f2bf(srcp[d * 512 + k * 128 + n]);
    } else {
        // features f32 -> bf16: 20000*64 = 1.28M elems, 8 per thread, 625 blocks exact
        int idx = (bid - 1890) * 256 + threadIdx.x;  // < 160000
        size_t b8 = (size_t)idx * 8;
        float4 a = *(const float4*)(features + b8);
        float4 b = *(const float4*)(features + b8 + 4);
        uint4 o;
        o.x = pack2bf(a.x, a.y);
        o.y = pack2bf(a.z, a.w);
        o.z = pack2bf(b.x, b.y);
        o.w = pack2bf(b.z, b.w);
        *(uint4*)(fbf + b8) = o;
    }
}

// ------ fused layer: M=32 nodes/block, 16 waves, 2 nodes/wave, pair-gather agg ------
// GEMM: ALL 16 waves — wave wv -> (row-tile wv>>3, col-tile wv&7); paired waves share
// Bt lines via L1. __launch_bounds__(1024,8) -> 2 blocks/CU co-resident so one block's
// MFMA overlaps the other's agg (separate pipes).
template <int DIN, bool OUTBF>
__global__ __launch_bounds__(1024, 8) void layer_fused(
    const ushort* __restrict__ hbf, const int* __restrict__ cursor,
    const uint* __restrict__ recs, int woff,
    const ushort* __restrict__ Bt, const float* __restrict__ bias,
    void* __restrict__ hout) {
    constexpr int KD = 4 * DIN;
    constexpr int PITCH = KD + 8;   // ushorts; 16B-aligned rows
    constexpr int B = 8;            // pairs per batch -> 16 edges
    constexpr int FPL = DIN / 32;   // features per lane (2 or 4)
    __shared__ __align__(16) ushort Ts[32 * PITCH];
    int wv = threadIdx.x >> 6, lane = threadIdx.x & 63;
    int l16 = lane & 15, quad = lane >> 4;
    int half = lane >> 5, l32 = lane & 31;
    int nb = blockIdx.x * 32;

    // ---- aggregation: 2 sequential nodes per wave ----
    for (int t = 0; t < 2; ++t) {
        int row = wv * 2 + t;
        int n = nb + row;
        int deg = __builtin_amdgcn_readfirstlane(cursor[n]);
        deg = deg < SLOT ? deg : SLOT;  // safety clamp
        size_t base = (size_t)n * SLOT;

        float acc[4 * FPL];
#pragma unroll
        for (int j = 0; j < 4 * FPL; ++j) acc[j] = 0.f;

        for (int i = 0; i < deg; i += 2 * B) {
            int s[B];
            uint wlo[B], whi[B];
            uint2 hv[B];  // DIN==64 uses only .x
#pragma unroll
            for (int u = 0; u < B; ++u) {
                int ii = i + 2 * u + half;  // uniform within each half-wave
                bool ok = ii < deg;
                size_t idx = base + (ok ? ii : 0);
                const uint* r = recs + idx * 8;
                s[u] = (int)r[0];
                uint2 wp = *(const uint2*)(r + woff);
                wlo[u] = ok ? wp.x : 0u;
                whi[u] = ok ? wp.y : 0u;
            }
#pragma unroll
            for (int u = 0; u < B; ++u) {
                const ushort* rowp = hbf + (size_t)s[u] * DIN + l32 * FPL;
                if (DIN == 64)
                    hv[u].x = *(const uint*)rowp;
                else
                    hv[u] = *(const uint2*)rowp;
            }
#pragma unroll
            for (int u = 0; u < B; ++u) {
                float2 wa = h2f2(wlo[u]);
                float2 wb = h2f2(whi[u]);
                float w0 = wa.x, w1 = wa.y, w2 = wb.x, w3 = wb.y;
                float fx0 = bf2f_lo(hv[u].x), fx1 = bf2f_hi(hv[u].x);
                if (DIN == 64) {
                    acc[0] += w0 * fx0; acc[1] += w0 * fx1;
                    acc[2] += w1 * fx0; acc[3] += w1 * fx1;
                    acc[4] += w2 * fx0; acc[5] += w2 * fx1;
                    acc[6] += w3 * fx0; acc[7] += w3 * fx1;
                } else {
                    float fx2 = bf2f_lo(hv[u].y), fx3 = bf2f_hi(hv[u].y);
                    acc[0] += w0 * fx0;  acc[1] += w0 * fx1;
                    acc[2] += w0 * fx2;  acc[3] += w0 * fx3;
                    acc[4] += w1 * fx0;  acc[5] += w1 * fx1;
                    acc[6] += w1 * fx2;  acc[7] += w1 * fx3;
                    acc[8] += w2 * fx0;  acc[9] += w2 * fx1;
                    acc[10] += w2 * fx2; acc[11] += w2 * fx3;
                    acc[12] += w3 * fx0; acc[13] += w3 * fx1;
                    acc[14] += w3 * fx2; acc[15] += w3 * fx3;
                }
            }
        }
        // cross-half combine
#pragma unroll
        for (int j = 0; j < 4 * FPL; ++j) acc[j] += __shfl_xor(acc[j], 32);

        if (half == 0) {
#pragma unroll
            for (int k = 0; k < 4; ++k) {
                if (DIN == 64) {
                    ushort2 p;
                    p.x = f2bf(acc[k * 2 + 0]);
                    p.y = f2bf(acc[k * 2 + 1]);
                    *(ushort2*)(Ts + row * PITCH + k * DIN + l32 * 2) = p;
                } else {
                    ushort4 p;
                    p.x = f2bf(acc[k * 4 + 0]);
                    p.y = f2bf(acc[k * 4 + 1]);
                    p.z = f2bf(acc[k * 4 + 2]);
                    p.w = f2bf(acc[k * 4 + 3]);
                    *(ushort4*)(Ts + row * PITCH + k * DIN + l32 * 4) = p;
                }
            }
        }
    }
    __syncthreads();

    // ---- GEMM phase: 16 waves, wave wv -> row-tile (wv>>3), col-tile (wv&7) ----
    {
        int rt = wv >> 3;
        int c0 = (wv & 7) * 16;
        f32x4 acc2 = (f32x4){0.f, 0.f, 0.f, 0.f};
#pragma unroll 4
        for (int k0 = 0; k0 < KD; k0 += 32) {
            bf16x8 af = *(const bf16x8*)(Ts + (rt * 16 + l16) * PITCH + k0 + quad * 8);
            bf16x8 bfr = *(const bf16x8*)(Bt + (size_t)(c0 + l16) * KD + k0 + quad * 8);
            acc2 = __builtin_amdgcn_mfma_f32_16x16x32_bf16(af, bfr, acc2, 0, 0, 0);
        }
        int gn = c0 + l16;
        float bv = bias[gn];
#pragma unroll
        for (int i = 0; i < 4; ++i) {
            int gm = nb + rt * 16 + quad * 4 + i;
            float val = acc2[i] + bv;
            if (OUTBF)
                ((ushort*)hout)[(size_t)gm * 128 + gn] = f2bf(val);
            else
                ((float*)hout)[(size_t)gm * 128 + gn] = val;
        }
    }
}

extern "C" void kernel_launch(void* const* d_in, const int* in_sizes, int n_in,
                              void* d_out, int out_size, void* d_ws, size_t ws_size,
                              hipStream_t stream) {
    const float* features = (const float*)d_in[0];
    const float* pseudo = (const float*)d_in[1];
    const int* src = (const int*)d_in[2];
    const int* dst = (const int*)d_in[3];
    const float* fc_w[3] = {(const float*)d_in[4], (const float*)d_in[10], (const float*)d_in[16]};
    const float* mu[3] = {(const float*)d_in[5], (const float*)d_in[11], (const float*)d_in[17]};
    const float* isg[3] = {(const float*)d_in[6], (const float*)d_in[12], (const float*)d_in[18]};
    const float* bias[3] = {(const float*)d_in[7], (const float*)d_in[13], (const float*)d_in[19]};
    const float* pw[3] = {(const float*)d_in[8], (const float*)d_in[14], (const float*)d_in[20]};
    const float* pb[3] = {(const float*)d_in[9], (const float*)d_in[15], (const float*)d_in[21]};

    char* ws = (char*)d_ws;
    auto alloc = [&](size_t bytes) -> void* {
        void* p = (void*)ws;
        ws += (bytes + 255) & ~(size_t)255;
        return p;
    };
    int* cursor = (int*)alloc((size_t)NN * 4);
    uint* recs = (uint*)alloc((size_t)NN * SLOT * 32);   // 32B record per slot
    ushort* fbf = (ushort*)alloc((size_t)NN * 64 * 2);   // features in bf16
    ushort* w2t_0 = (ushort*)alloc((size_t)128 * 256 * 2);
    ushort* w2t_1 = (ushort*)alloc((size_t)128 * 512 * 2);
    ushort* w2t_2 = (ushort*)alloc((size_t)128 * 512 * 2);
    ushort* h1 = (ushort*)alloc((size_t)NN * 128 * 2);
    ushort* h2 = (ushort*)alloc((size_t)NN * 128 * 2);

    hipMemsetAsync(cursor, 0, (size_t)NN * 4, stream);
    EdgeParams P;
    P.pw0 = pw[0]; P.pb0 = pb[0]; P.mu0 = mu[0]; P.is0 = isg[0];
    P.pw1 = pw[1]; P.pb1 = pb[1]; P.mu1 = mu[1]; P.is1 = isg[1];
    P.pw2 = pw[2]; P.pb2 = pb[2]; P.mu2 = mu[2]; P.is2 = isg[2];
    fill_prep<<<2515, 256, 0, stream>>>(dst, src, pseudo, P, cursor, recs, features, fbf,
                                        fc_w[0], fc_w[1], fc_w[2], w2t_0, w2t_1, w2t_2);

    const int GB = NN / 32;  // 625 blocks, 16 waves each, 2 nodes/wave

    layer_fused<64, true><<<GB, 1024, 0, stream>>>(
        fbf, cursor, recs, 2, w2t_0, bias[0], h1);
    layer_fused<128, true><<<GB, 1024, 0, stream>>>(
        h1, cursor, recs, 4, w2t_1, bias[1], h2);
    layer_fused<128, false><<<GB, 1024, 0, stream>>>(
        h2, cursor, recs, 6, w2t_2, bias[2], (float*)d_out);
}

// Round 13
// 233.141 us; speedup vs baseline: 1.3834x; 1.1146x over previous
//
#include <hip/hip_runtime.h>
#include <hip/hip_bf16.h>
#include <hip/hip_fp16.h>
#include <math.h>

#define NN 20000
#define NE 320000
#define SLOT 64  // padded-CSR slots per node; P(deg>64) ~ 1e-18 at mean 16

typedef __attribute__((ext_vector_type(8))) short bf16x8;
typedef __attribute__((ext_vector_type(4))) float f32x4;

__device__ inline float bf2f_lo(uint v) {
    union { uint i; float f; } c; c.i = v << 16; return c.f;
}
__device__ inline float bf2f_hi(uint v) {
    union { uint i; float f; } c; c.i = v & 0xffff0000u; return c.f;
}
__device__ inline ushort f2bf(float f) {
    __hip_bfloat16 h = __float2bfloat16(f);
    return *reinterpret_cast<ushort*>(&h);
}
__device__ inline uint pack2bf(float a, float b) {
    return (uint)f2bf(a) | ((uint)f2bf(b) << 16);
}
__device__ inline float2 h2f2(uint u) {  // 2 packed halves -> 2 floats
    union { uint i; __half2 h; } c; c.i = u;
    return __half22float2(c.h);
}
__device__ inline ushort f2h(float f) {
    __half h = __float2half_rn(f);
    return *reinterpret_cast<ushort*>(&h);
}

__device__ inline float fast_tanh(float x) {
    x = fminf(fmaxf(x, -9.f), 9.f);
    float e = __expf(2.f * x);
    return 1.f - 2.f / (e + 1.f);
}

struct EdgeParams {
    const float *pw0, *pb0, *mu0, *is0;
    const float *pw1, *pb1, *mu1, *is1;
    const float *pw2, *pb2, *mu2, *is2;
};

__device__ inline void layer_w(float p0, float p1, const float* pw, const float* pb,
                               const float* mu, const float* is, float* out4) {
    float u0 = fast_tanh(p0 * pw[0] + p1 * pw[2] + pb[0]);
    float u1 = fast_tanh(p0 * pw[1] + p1 * pw[3] + pb[1]);
#pragma unroll
    for (int k = 0; k < 4; ++k) {
        float d0 = (u0 - mu[k * 2 + 0]) * is[k * 2 + 0];
        float d1 = (u1 - mu[k * 2 + 1]) * is[k * 2 + 1];
        out4[k] = __expf(-0.5f * (d0 * d0 + d1 * d1));
    }
}

// ---- prep: edge records (blocks 0..1249) + weight transpose (1250..1889)
//      + features->bf16 (1890..2514) ----
__global__ void fill_prep(const int* __restrict__ dst, const int* __restrict__ src,
                          const float* __restrict__ pseudo, EdgeParams P,
                          int* __restrict__ cursor, uint* __restrict__ recs,
                          const float* __restrict__ features, ushort* __restrict__ fbf,
                          const float* __restrict__ f0, const float* __restrict__ f1,
                          const float* __restrict__ f2, ushort* __restrict__ w0,
                          ushort* __restrict__ w1, ushort* __restrict__ w2) {
    int bid = blockIdx.x;
    if (bid < 1250) {
        int e = bid * 256 + threadIdx.x;  // 1250*256 == NE exactly
        int n = dst[e];
        int pos = atomicAdd(&cursor[n], 1);
        if (pos < SLOT) {
            size_t slot = (size_t)n * SLOT + pos;
            float2 p = *(const float2*)(pseudo + (size_t)e * 2);  // contiguous read
            float w[4];
            uint pk0x, pk0y, pk1x, pk1y, pk2x, pk2y;
            layer_w(p.x, p.y, P.pw0, P.pb0, P.mu0, P.is0, w);
            pk0x = (uint)f2h(w[0]) | ((uint)f2h(w[1]) << 16);
            pk0y = (uint)f2h(w[2]) | ((uint)f2h(w[3]) << 16);
            layer_w(p.x, p.y, P.pw1, P.pb1, P.mu1, P.is1, w);
            pk1x = (uint)f2h(w[0]) | ((uint)f2h(w[1]) << 16);
            pk1y = (uint)f2h(w[2]) | ((uint)f2h(w[3]) << 16);
            layer_w(p.x, p.y, P.pw2, P.pb2, P.mu2, P.is2, w);
            pk2x = (uint)f2h(w[0]) | ((uint)f2h(w[1]) << 16);
            pk2y = (uint)f2h(w[2]) | ((uint)f2h(w[3]) << 16);
            uint* r = recs + slot * 8;
            *(uint4*)(r + 0) = make_uint4((uint)src[e], 0u, pk0x, pk0y);
            *(uint4*)(r + 4) = make_uint4(pk1x, pk1y, pk2x, pk2y);
        }
    } else if (bid < 1890) {
        int idx = (bid - 1250) * 256 + threadIdx.x;  // 640 blocks cover 163840 exactly
        const float* srcp;
        ushort* dstp;
        int din, KD, li;
        if (idx < 128 * 256) {
            srcp = f0; dstp = w0; din = 64; KD = 256; li = idx;
        } else if (idx < 128 * 256 + 128 * 512) {
            srcp = f1; dstp = w1; din = 128; KD = 512; li = idx - 128 * 256;
        } else {
            srcp = f2; dstp = w2; din = 128; KD = 512; li = idx - 128 * 256 - 128 * 512;
        }
        int n = li / KD;
        int r = li - n * KD;
        int k = r / din;
        int d = r - k * din;
        dstp[li] = f2bf(srcp[d * 512 + k * 128 + n]);
    } else {
        // features f32 -> bf16: 20000*64 = 1.28M elems, 8 per thread, 625 blocks exact
        int idx = (bid - 1890) * 256 + threadIdx.x;  // < 160000
        size_t b8 = (size_t)idx * 8;
        float4 a = *(const float4*)(features + b8);
        float4 b = *(const float4*)(features + b8 + 4);
        uint4 o;
        o.x = pack2bf(a.x, a.y);
        o.y = pack2bf(a.z, a.w);
        o.z = pack2bf(b.x, b.y);
        o.w = pack2bf(b.z, b.w);
        *(uint4*)(fbf + b8) = o;
    }
}

// ------ fused layer: R8 agg (16 waves, 1 node/wave, pair-gather) + K-SPLIT GEMM ------
// GEMM uses ALL 16 waves: wave wv -> col-tile (wv&7)*16, K-half (wv>>3).
// Upper K-half waves write f32x4 partials to LDS; lower waves add + store.
template <int DIN, bool OUTBF>
__global__ __launch_bounds__(1024, 8) void layer_fused(
    const ushort* __restrict__ hbf, const int* __restrict__ cursor,
    const uint* __restrict__ recs, int woff,
    const ushort* __restrict__ Bt, const float* __restrict__ bias,
    void* __restrict__ hout) {
    constexpr int KD = 4 * DIN;
    constexpr int PITCH = KD + 8;   // ushorts; 16B-aligned rows
    constexpr int B = 8;            // pairs per batch -> 16 edges
    constexpr int FPL = DIN / 32;   // features per lane (2 or 4)
    __shared__ __align__(16) ushort Ts[16 * PITCH];
    __shared__ __align__(16) f32x4 red[8][64];  // K-split partials (8 KB)
    int wv = threadIdx.x >> 6, lane = threadIdx.x & 63;
    int l16 = lane & 15, quad = lane >> 4;
    int half = lane >> 5, l32 = lane & 31;
    int nb = blockIdx.x * 16;
    int n = nb + wv;

    // ---- aggregation: one node per wave (R8 pair-gather) ----
    {
        int deg = __builtin_amdgcn_readfirstlane(cursor[n]);
        deg = deg < SLOT ? deg : SLOT;  // safety clamp
        size_t base = (size_t)n * SLOT;

        float acc[4 * FPL];
#pragma unroll
        for (int j = 0; j < 4 * FPL; ++j) acc[j] = 0.f;

        for (int i = 0; i < deg; i += 2 * B) {
            int s[B];
            uint wlo[B], whi[B];
            uint2 hv[B];  // DIN==64 uses only .x
#pragma unroll
            for (int u = 0; u < B; ++u) {
                int ii = i + 2 * u + half;  // uniform within each half-wave
                bool ok = ii < deg;
                size_t idx = base + (ok ? ii : 0);
                const uint* r = recs + idx * 8;
                s[u] = (int)r[0];
                uint2 wp = *(const uint2*)(r + woff);
                wlo[u] = ok ? wp.x : 0u;
                whi[u] = ok ? wp.y : 0u;
            }
#pragma unroll
            for (int u = 0; u < B; ++u) {
                const ushort* rowp = hbf + (size_t)s[u] * DIN + l32 * FPL;
                if (DIN == 64)
                    hv[u].x = *(const uint*)rowp;
                else
                    hv[u] = *(const uint2*)rowp;
            }
#pragma unroll
            for (int u = 0; u < B; ++u) {
                float2 wa = h2f2(wlo[u]);
                float2 wb = h2f2(whi[u]);
                float w0 = wa.x, w1 = wa.y, w2 = wb.x, w3 = wb.y;
                float fx0 = bf2f_lo(hv[u].x), fx1 = bf2f_hi(hv[u].x);
                if (DIN == 64) {
                    acc[0] += w0 * fx0; acc[1] += w0 * fx1;
                    acc[2] += w1 * fx0; acc[3] += w1 * fx1;
                    acc[4] += w2 * fx0; acc[5] += w2 * fx1;
                    acc[6] += w3 * fx0; acc[7] += w3 * fx1;
                } else {
                    float fx2 = bf2f_lo(hv[u].y), fx3 = bf2f_hi(hv[u].y);
                    acc[0] += w0 * fx0;  acc[1] += w0 * fx1;
                    acc[2] += w0 * fx2;  acc[3] += w0 * fx3;
                    acc[4] += w1 * fx0;  acc[5] += w1 * fx1;
                    acc[6] += w1 * fx2;  acc[7] += w1 * fx3;
                    acc[8] += w2 * fx0;  acc[9] += w2 * fx1;
                    acc[10] += w2 * fx2; acc[11] += w2 * fx3;
                    acc[12] += w3 * fx0; acc[13] += w3 * fx1;
                    acc[14] += w3 * fx2; acc[15] += w3 * fx3;
                }
            }
        }
        // cross-half combine
#pragma unroll
        for (int j = 0; j < 4 * FPL; ++j) acc[j] += __shfl_xor(acc[j], 32);

        if (half == 0) {
#pragma unroll
            for (int k = 0; k < 4; ++k) {
                if (DIN == 64) {
                    ushort2 p;
                    p.x = f2bf(acc[k * 2 + 0]);
                    p.y = f2bf(acc[k * 2 + 1]);
                    *(ushort2*)(Ts + wv * PITCH + k * DIN + l32 * 2) = p;
                } else {
                    ushort4 p;
                    p.x = f2bf(acc[k * 4 + 0]);
                    p.y = f2bf(acc[k * 4 + 1]);
                    p.z = f2bf(acc[k * 4 + 2]);
                    p.w = f2bf(acc[k * 4 + 3]);
                    *(ushort4*)(Ts + wv * PITCH + k * DIN + l32 * 4) = p;
                }
            }
        }
    }
    __syncthreads();

    // ---- GEMM phase: 16 waves, K-split. wave wv -> col (wv&7)*16, K-half (wv>>3) ----
    {
        constexpr int KH = KD / 2;
        int kh = wv >> 3;
        int ct = wv & 7;
        int c0 = ct * 16;
        f32x4 acc2 = (f32x4){0.f, 0.f, 0.f, 0.f};
        int kbeg = kh * KH;
#pragma unroll 4
        for (int k0 = kbeg; k0 < kbeg + KH; k0 += 32) {
            bf16x8 af = *(const bf16x8*)(Ts + l16 * PITCH + k0 + quad * 8);
            bf16x8 bfr = *(const bf16x8*)(Bt + (size_t)(c0 + l16) * KD + k0 + quad * 8);
            acc2 = __builtin_amdgcn_mfma_f32_16x16x32_bf16(af, bfr, acc2, 0, 0, 0);
        }
        if (kh == 1) red[ct][lane] = acc2;
        __syncthreads();
        if (kh == 0) {
            f32x4 other = red[ct][lane];
            int gn = c0 + l16;
            float bv = bias[gn];
#pragma unroll
            for (int i = 0; i < 4; ++i) {
                int gm = nb + quad * 4 + i;
                float val = acc2[i] + other[i] + bv;
                if (OUTBF)
                    ((ushort*)hout)[(size_t)gm * 128 + gn] = f2bf(val);
                else
                    ((float*)hout)[(size_t)gm * 128 + gn] = val;
            }
        }
    }
}

extern "C" void kernel_launch(void* const* d_in, const int* in_sizes, int n_in,
                              void* d_out, int out_size, void* d_ws, size_t ws_size,
                              hipStream_t stream) {
    const float* features = (const float*)d_in[0];
    const float* pseudo = (const float*)d_in[1];
    const int* src = (const int*)d_in[2];
    const int* dst = (const int*)d_in[3];
    const float* fc_w[3] = {(const float*)d_in[4], (const float*)d_in[10], (const float*)d_in[16]};
    const float* mu[3] = {(const float*)d_in[5], (const float*)d_in[11], (const float*)d_in[17]};
    const float* isg[3] = {(const float*)d_in[6], (const float*)d_in[12], (const float*)d_in[18]};
    const float* bias[3] = {(const float*)d_in[7], (const float*)d_in[13], (const float*)d_in[19]};
    const float* pw[3] = {(const float*)d_in[8], (const float*)d_in[14], (const float*)d_in[20]};
    const float* pb[3] = {(const float*)d_in[9], (const float*)d_in[15], (const float*)d_in[21]};

    char* ws = (char*)d_ws;
    auto alloc = [&](size_t bytes) -> void* {
        void* p = (void*)ws;
        ws += (bytes + 255) & ~(size_t)255;
        return p;
    };
    int* cursor = (int*)alloc((size_t)NN * 4);
    uint* recs = (uint*)alloc((size_t)NN * SLOT * 32);   // 32B record per slot
    ushort* fbf = (ushort*)alloc((size_t)NN * 64 * 2);   // features in bf16
    ushort* w2t_0 = (ushort*)alloc((size_t)128 * 256 * 2);
    ushort* w2t_1 = (ushort*)alloc((size_t)128 * 512 * 2);
    ushort* w2t_2 = (ushort*)alloc((size_t)128 * 512 * 2);
    ushort* h1 = (ushort*)alloc((size_t)NN * 128 * 2);
    ushort* h2 = (ushort*)alloc((size_t)NN * 128 * 2);

    hipMemsetAsync(cursor, 0, (size_t)NN * 4, stream);
    EdgeParams P;
    P.pw0 = pw[0]; P.pb0 = pb[0]; P.mu0 = mu[0]; P.is0 = isg[0];
    P.pw1 = pw[1]; P.pb1 = pb[1]; P.mu1 = mu[1]; P.is1 = isg[1];
    P.pw2 = pw[2]; P.pb2 = pb[2]; P.mu2 = mu[2]; P.is2 = isg[2];
    fill_prep<<<2515, 256, 0, stream>>>(dst, src, pseudo, P, cursor, recs, features, fbf,
                                        fc_w[0], fc_w[1], fc_w[2], w2t_0, w2t_1, w2t_2);

    const int GB = NN / 16;  // 1250 blocks, 16 waves each, 1 node/wave

    layer_fused<64, true><<<GB, 1024, 0, stream>>>(
        fbf, cursor, recs, 2, w2t_0, bias[0], h1);
    layer_fused<128, true><<<GB, 1024, 0, stream>>>(
        h1, cursor, recs, 4, w2t_1, bias[1], h2);
    layer_fused<128, false><<<GB, 1024, 0, stream>>>(
        h2, cursor, recs, 6, w2t_2, bias[2], (float*)d_out);
}